// Round 4
// baseline (139.342 us; speedup 1.0000x reference)
//
#include <hip/hip_runtime.h>

#define HDIM 128
#define NPOS 1024
#define NCOL 512
#define LN_EPS 1e-3f
#define NBLK 256

// Phase mask bits for the probe/ablation template (rule #17: every skipped
// phase's outputs are still consumed by later live code or separate scratch
// buffers, so nothing upstream gets DCE'd in the FULL instantiation).
#define DO_P1  1
#define DO_P2  2
#define DO_P3  4
#define DO_BAR 8

#define AS_STR 36
#define BS_STR 68

union FusedSmem {
    struct {
        float xs[4][HDIM];
        float ds[4][HDIM];
        float partm[8], partp[8], partv[8], mus[4];
    } p1;
    struct { float As[128 * AS_STR]; float Bs[128 * BS_STR]; } s;
    struct { float comb[8 * 256]; float redr[512]; float redc[1024]; } r;
};

__device__ __forceinline__ void st_sys(float* p, float v) {
    __hip_atomic_store(p, v, __ATOMIC_RELAXED, __HIP_MEMORY_SCOPE_SYSTEM);
}
__device__ __forceinline__ float ld_sys(const float* p) {
    return __hip_atomic_load(p, __ATOMIC_RELAXED, __HIP_MEMORY_SCOPE_SYSTEM);
}
__device__ __forceinline__ void st_sys_i(int* p, int v) {
    __hip_atomic_store(p, v, __ATOMIC_RELAXED, __HIP_MEMORY_SCOPE_SYSTEM);
}
__device__ __forceinline__ int ld_sys_i(const int* p) {
    return __hip_atomic_load(p, __ATOMIC_RELAXED, __HIP_MEMORY_SCOPE_SYSTEM);
}

__device__ __forceinline__ int seg_of(int i, const int* __restrict__ lens, int n_seq) {
    int cum = 0;
    for (int s = 0; s < n_seq; ++s) { cum += lens[s]; if (i < cum) return s; }
    return n_seq - 1;
}

// ---------------------------------------------------------------------------
// Hierarchical 2-level grid barrier. Round-3's barrier had all 256 blocks
// polling ONE L3 line (system-scope loads serialize at the L3 bank; suspected
// ~10us/barrier exit). Here: 8 groups x 32 blocks. Arrival: group counter
// (own 128B line) -> last-of-group bumps global counter -> last group writes
// 8 release flags (own 128B lines). Spin: 32 pollers per flag line only.
// Monotonic epochs (1,2) avoid any reset between the two barriers.
// Arena layout (uint words): grp_cnt[g]=g*32, grp_flag[g]=256+g*32, glob=512.
// ---------------------------------------------------------------------------
__device__ __forceinline__ void grid_sync_h(unsigned int* arena, unsigned int epoch) {
    __syncthreads();                      // drains vmcnt: block's stores at L3
    if (threadIdx.x == 0) {
        const unsigned g = blockIdx.x >> 5;
        unsigned int* gcnt  = arena + g * 32;
        unsigned int* gflag = arena + 256 + g * 32;
        unsigned int* glob  = arena + 512;
        unsigned old = __hip_atomic_fetch_add(gcnt, 1u, __ATOMIC_RELAXED, __HIP_MEMORY_SCOPE_SYSTEM);
        if (old == epoch * 32u - 1u) {                    // last block of group
            unsigned gold = __hip_atomic_fetch_add(glob, 1u, __ATOMIC_RELAXED, __HIP_MEMORY_SCOPE_SYSTEM);
            if (gold == epoch * 8u - 1u) {                // last group: release
                #pragma unroll
                for (int i = 0; i < 8; ++i)
                    __hip_atomic_store(arena + 256 + i * 32, epoch,
                                       __ATOMIC_RELAXED, __HIP_MEMORY_SCOPE_SYSTEM);
            }
        }
        while (__hip_atomic_load(gflag, __ATOMIC_RELAXED, __HIP_MEMORY_SCOPE_SYSTEM) < epoch)
            __builtin_amdgcn_s_sleep(4);
    }
    __syncthreads();
}

template<int MODE>
__global__ __launch_bounds__(512, 2) void fused(
          const float* __restrict__ seq_feat, const float* __restrict__ col_feat,
          const float* __restrict__ Ws, const float* __restrict__ bsv,
          const float* __restrict__ Wc, const float* __restrict__ bcv,
          const float* __restrict__ Wm, const float* __restrict__ bmv,
          const float* __restrict__ gam, const float* __restrict__ Wo,
          const int* __restrict__ lens, int n_seq,
          float* __restrict__ AcT, float* __restrict__ BcT,
          float* __restrict__ p_arr, float* __restrict__ v_arr,
          float* __restrict__ q_arr, float* __restrict__ w_arr,
          float* __restrict__ sums, int* __restrict__ segid,
          float* __restrict__ out, unsigned int* __restrict__ arena)
{
    __shared__ FusedSmem sm;
    const int t = threadIdx.x;
    const int b = blockIdx.x;

    // =================== phase 1: per-row precompute ===================
    if constexpr ((MODE & DO_P1) != 0) {
        const int h    = t & 127;
        const int r    = t >> 7;
        const int wv   = t >> 6;
        const int lane = t & 63;

        {   // housekeeping: zero accumulators + fill segid LUT (system-scope)
            const int nsums = NPOS + n_seq * NCOL;
            int idx = b * 512 + t;
            if (idx < nsums) st_sys(&sums[idx], 0.f);
            int idx2 = idx - nsums;
            if (idx2 >= 0 && idx2 < NPOS) st_sys_i(&segid[idx2], seg_of(idx2, lens, n_seq));
        }

        for (int pass = 0; pass < 2; ++pass) {
            const int unit = b + NBLK * pass;          // 384 units over 256 blocks
            if (unit < (NPOS + NCOL) / 4) {
                const bool  is_seq = (unit < NPOS / 4);
                const int   i0 = (is_seq ? unit : unit - NPOS / 4) * 4;
                const float* X  = is_seq ? seq_feat : col_feat;
                const float* W1 = is_seq ? Ws : Wc;
                const float* b1 = is_seq ? bsv : bcv;

                if (t < 128) {
                    int rr = t >> 5, k4 = (t & 31) * 4;
                    *(float4*)&sm.p1.xs[rr][k4] = *(const float4*)&X[(i0 + rr) * HDIM + k4];
                }
                __syncthreads();

                float d;
                {
                    float a0 = 0.f, a1 = 0.f, a2 = 0.f, a3 = 0.f;
                    #pragma unroll 8
                    for (int k = 0; k < HDIM; k += 4) {
                        float4 x = *(const float4*)&sm.p1.xs[r][k];
                        float w0 = W1[(k + 0) * HDIM + h];
                        float w1 = W1[(k + 1) * HDIM + h];
                        float w2 = W1[(k + 2) * HDIM + h];
                        float w3 = W1[(k + 3) * HDIM + h];
                        a0 += x.x * w0; a1 += x.y * w1; a2 += x.z * w2; a3 += x.w * w3;
                    }
                    d = fmaxf(b1[h] + ((a0 + a1) + (a2 + a3)), 0.f);
                }
                sm.p1.ds[r][h] = d;
                __syncthreads();

                float aa;
                {
                    float a0 = 0.f, a1 = 0.f, a2 = 0.f, a3 = 0.f;
                    #pragma unroll 8
                    for (int k = 0; k < HDIM; k += 4) {
                        float4 x = *(const float4*)&sm.p1.ds[r][k];
                        float w0 = Wm[(k + 0) * HDIM + h];
                        float w1 = Wm[(k + 1) * HDIM + h];
                        float w2 = Wm[(k + 2) * HDIM + h];
                        float w3 = Wm[(k + 3) * HDIM + h];
                        a0 += x.x * w0; a1 += x.y * w1; a2 += x.z * w2; a3 += x.w * w3;
                    }
                    aa = (is_seq ? 0.f : bmv[h]) + ((a0 + a1) + (a2 + a3));
                }

                {
                    float s = aa;
                    #pragma unroll
                    for (int off = 32; off; off >>= 1) s += __shfl_xor(s, off, 64);
                    if (lane == 0) sm.p1.partm[wv] = s;
                }
                __syncthreads();
                if (t < 4) sm.p1.mus[t] = (sm.p1.partm[2 * t] + sm.p1.partm[2 * t + 1]) * (1.f / HDIM);
                __syncthreads();

                const float a  = aa - sm.p1.mus[r];
                const float gw = gam[h] * Wo[h];

                {
                    float sp = a * gw, sv = a * a;
                    #pragma unroll
                    for (int off = 32; off; off >>= 1) {
                        sp += __shfl_xor(sp, off, 64);
                        sv += __shfl_xor(sv, off, 64);
                    }
                    if (lane == 0) { sm.p1.partp[wv] = sp; sm.p1.partv[wv] = sv; }
                }
                sm.p1.xs[r][h] = a;
                __syncthreads();
                if (t < 4) {
                    st_sys(&(is_seq ? p_arr : q_arr)[i0 + t], sm.p1.partp[2 * t] + sm.p1.partp[2 * t + 1]);
                    st_sys(&(is_seq ? v_arr : w_arr)[i0 + t], (sm.p1.partv[2 * t] + sm.p1.partv[2 * t + 1]) * (1.f / HDIM));
                }
                if (t < 128) {
                    float* dst = is_seq ? &AcT[t * NPOS + i0] : &BcT[t * NCOL + i0];
                    st_sys(dst + 0, sm.p1.xs[0][t]);
                    st_sys(dst + 1, sm.p1.xs[1][t]);
                    st_sys(dst + 2, sm.p1.xs[2][t]);
                    st_sys(dst + 3, sm.p1.xs[3][t]);
                }
            }
            __syncthreads();
        }
    }
    if constexpr ((MODE & DO_BAR) != 0) grid_sync_h(arena, 1u);

    // =================== phase 2: fused GEMM + exp + sums ===================
    float* rowsum = sums;
    float* segsum = sums + NPOS;
    const int tt = t & 255;
    const int tc = tt & 15;
    const int tr = tt >> 4;
    const int i0 = (b >> 3) * 32;
    const int j0 = (b & 7) * 64;
    float e[2][4] = {};
    if constexpr ((MODE & DO_P2) != 0) {
        const int kbase = (t >> 8) * 64;

        #pragma unroll
        for (int u = 0; u < 2; ++u) {
            int fid = t + 512 * u;
            int k = fid >> 3, m4 = fid & 7;
            const float* src = &AcT[k * NPOS + i0 + 4 * m4];
            float4 tmp = make_float4(ld_sys(src + 0), ld_sys(src + 1), ld_sys(src + 2), ld_sys(src + 3));
            *(float4*)&sm.s.As[k * AS_STR + 4 * m4] = tmp;
        }
        #pragma unroll
        for (int u = 0; u < 4; ++u) {
            int fid = t + 512 * u;
            int k = fid >> 4, n4 = fid & 15;
            const float* src = &BcT[k * NCOL + j0 + 4 * n4];
            float4 tmp = make_float4(ld_sys(src + 0), ld_sys(src + 1), ld_sys(src + 2), ld_sys(src + 3));
            *(float4*)&sm.s.Bs[k * BS_STR + 4 * n4] = tmp;
        }
        __syncthreads();

        float acc[8] = {0.f, 0.f, 0.f, 0.f, 0.f, 0.f, 0.f, 0.f};
        #pragma unroll 4
        for (int k = kbase; k < kbase + 64; ++k) {
            float2 a2 = *(const float2*)&sm.s.As[k * AS_STR + 2 * tr];
            float4 b4 = *(const float4*)&sm.s.Bs[k * BS_STR + 4 * tc];
            acc[0] += a2.x * b4.x; acc[1] += a2.x * b4.y; acc[2] += a2.x * b4.z; acc[3] += a2.x * b4.w;
            acc[4] += a2.y * b4.x; acc[5] += a2.y * b4.y; acc[6] += a2.y * b4.z; acc[7] += a2.y * b4.w;
        }

        const int seg_lo = ld_sys_i(&segid[i0]);
        const int seg_hi = ld_sys_i(&segid[i0 + 31]);
        __syncthreads();

        if (t >= 256) {
            #pragma unroll
            for (int j = 0; j < 8; ++j) sm.r.comb[j * 256 + tt] = acc[j];
        }
        __syncthreads();

        if (t < 256) {
            #pragma unroll
            for (int j = 0; j < 8; ++j) acc[j] += sm.r.comb[j * 256 + tt];

            const int jj = j0 + 4 * tc;
            float4 q4 = make_float4(ld_sys(&q_arr[jj]), ld_sys(&q_arr[jj + 1]),
                                    ld_sys(&q_arr[jj + 2]), ld_sys(&q_arr[jj + 3]));
            float4 w4 = make_float4(ld_sys(&w_arr[jj]), ld_sys(&w_arr[jj + 1]),
                                    ld_sys(&w_arr[jj + 2]), ld_sys(&w_arr[jj + 3]));
            float rs[2];
            #pragma unroll
            for (int mm = 0; mm < 2; ++mm) {
                const int i = i0 + 2 * tr + mm;
                const float pi = ld_sys(&p_arr[i]);
                const float vi = ld_sys(&v_arr[i]);
                e[mm][0] = __expf((pi + q4.x) * rsqrtf(vi + w4.x + acc[4*mm+0] * (2.f/HDIM) + LN_EPS));
                e[mm][1] = __expf((pi + q4.y) * rsqrtf(vi + w4.y + acc[4*mm+1] * (2.f/HDIM) + LN_EPS));
                e[mm][2] = __expf((pi + q4.z) * rsqrtf(vi + w4.z + acc[4*mm+2] * (2.f/HDIM) + LN_EPS));
                e[mm][3] = __expf((pi + q4.w) * rsqrtf(vi + w4.w + acc[4*mm+3] * (2.f/HDIM) + LN_EPS));
                rs[mm] = e[mm][0] + e[mm][1] + e[mm][2] + e[mm][3];
            }
            sm.r.redr[(2 * tr + 0) * 16 + tc] = rs[0];
            sm.r.redr[(2 * tr + 1) * 16 + tc] = rs[1];
            #pragma unroll
            for (int u = 0; u < 4; ++u)
                sm.r.redc[(4 * tc + u) * 16 + tr] = e[0][u] + e[1][u];
        }
        __syncthreads();

        if (t < 32) {
            float s = 0.f;
            #pragma unroll
            for (int m = 0; m < 16; ++m) s += sm.r.redr[t * 16 + m];
            atomicAdd(&rowsum[i0 + t], s);
        } else if (t >= 32 && t < 96 && seg_lo == seg_hi) {
            int c = t - 32;
            float s = 0.f;
            #pragma unroll
            for (int m = 0; m < 16; ++m) s += sm.r.redc[c * 16 + m];
            atomicAdd(&segsum[seg_lo * NCOL + j0 + c], s);
        }
        if (seg_lo != seg_hi && t < 256) {
            #pragma unroll
            for (int mm = 0; mm < 2; ++mm) {
                const int i = i0 + 2 * tr + mm;
                const int sg = ld_sys_i(&segid[i]);
                #pragma unroll
                for (int u = 0; u < 4; ++u)
                    atomicAdd(&segsum[sg * NCOL + j0 + 4 * tc + u], e[mm][u]);
            }
        }
    }
    if constexpr ((MODE & DO_BAR) != 0) grid_sync_h(arena, 2u);

    // ====== phase 3: finalize own tile from registers ======
    if constexpr ((MODE & DO_P3) != 0) {
        if (t < 256) {
            const int jj = j0 + 4 * tc;
            #pragma unroll
            for (int mm = 0; mm < 2; ++mm) {
                const int i = i0 + 2 * tr + mm;
                const float invr = 1.f / ld_sys(&rowsum[i]);
                const int sg = ld_sys_i(&segid[i]);
                const float s0 = ld_sys(&segsum[sg * NCOL + jj + 0]);
                const float s1 = ld_sys(&segsum[sg * NCOL + jj + 1]);
                const float s2 = ld_sys(&segsum[sg * NCOL + jj + 2]);
                const float s3 = ld_sys(&segsum[sg * NCOL + jj + 3]);
                float4 o;
                { float mc = e[mm][0] * invr, ms = e[mm][0] / s0; o.x = mc + ms - mc * ms; }
                { float mc = e[mm][1] * invr, ms = e[mm][1] / s1; o.y = mc + ms - mc * ms; }
                { float mc = e[mm][2] * invr, ms = e[mm][2] / s2; o.z = mc + ms - mc * ms; }
                { float mc = e[mm][3] * invr, ms = e[mm][3] / s3; o.w = mc + ms - mc * ms; }
                *(float4*)&out[i * NCOL + jj] = o;
            }
        }
    }
}

// ===========================================================================
extern "C" void kernel_launch(void* const* d_in, const int* in_sizes, int n_in,
                              void* d_out, int out_size, void* d_ws, size_t ws_size,
                              hipStream_t stream) {
    const float* seq_feat = (const float*)d_in[0];
    const float* col_feat = (const float*)d_in[1];
    const int*   lens     = (const int*)d_in[2];
    const float* Ws   = (const float*)d_in[3];
    const float* bs   = (const float*)d_in[4];
    const float* Wc   = (const float*)d_in[5];
    const float* bc   = (const float*)d_in[6];
    const float* Wm   = (const float*)d_in[7];
    const float* bm   = (const float*)d_in[8];
    const float* gam  = (const float*)d_in[9];
    const float* Wo   = (const float*)d_in[11];
    float* out = (float*)d_out;
    const int n_seq = in_sizes[2];

    float* ws     = (float*)d_ws;
    float* AcT    = ws;                         // 128*1024
    float* BcT    = AcT + HDIM * NPOS;          // 128*512
    float* p      = BcT + HDIM * NCOL;          // 1024
    float* v      = p + NPOS;                   // 1024
    float* q      = v + NPOS;                   // 512
    float* w      = q + NCOL;                   // 512
    float* sums   = w + NCOL;                   // rowsum 1024 + segsum n_seq*512
    int*   segid  = (int*)(sums + NPOS + n_seq * NCOL);   // 1024 ints
    unsigned int* arena0 = (unsigned int*)(segid + NPOS); // 1024 words (BAR probe)
    unsigned int* arena1 = arena0 + 1024;                 // 1024 words (FULL)
    float* sums2  = (float*)(arena1 + 1024);              // probe scratch sums
    float* out2   = sums2 + NPOS + 8 * NCOL;              // probe scratch out (unused by probes' P3)

    // zero both barrier arenas each replay
    hipMemsetAsync(arena0, 0, 2048 * sizeof(unsigned int), stream);

    // --- probe dispatches (diagnostic round: per-phase dur_us via rocprof) ---
    // P1 only
    hipLaunchKernelGGL((fused<DO_P1>), dim3(NBLK), dim3(512), 0, stream,
                       seq_feat, col_feat, Ws, bs, Wc, bc, Wm, bm, gam, Wo,
                       lens, n_seq, AcT, BcT, p, v, q, w, sums2, segid, out2, arena0);
    // P2 only (consumes P1's outputs across the dispatch boundary; scratch sums)
    hipLaunchKernelGGL((fused<DO_P2>), dim3(NBLK), dim3(512), 0, stream,
                       seq_feat, col_feat, Ws, bs, Wc, bc, Wm, bm, gam, Wo,
                       lens, n_seq, AcT, BcT, p, v, q, w, sums2, segid, out2, arena0);
    // barriers only (hierarchical, zero-load cost)
    hipLaunchKernelGGL((fused<DO_BAR>), dim3(NBLK), dim3(512), 0, stream,
                       seq_feat, col_feat, Ws, bs, Wc, bc, Wm, bm, gam, Wo,
                       lens, n_seq, AcT, BcT, p, v, q, w, sums2, segid, out2, arena0);
    // --- the real kernel: full fusion with hierarchical barrier ---
    hipLaunchKernelGGL((fused<DO_P1 | DO_P2 | DO_P3 | DO_BAR>), dim3(NBLK), dim3(512), 0, stream,
                       seq_feat, col_feat, Ws, bs, Wc, bc, Wm, bm, gam, Wo,
                       lens, n_seq, AcT, BcT, p, v, q, w, sums, segid, out, arena1);
}

// Round 5
// 98.080 us; speedup vs baseline: 1.4207x; 1.4207x over previous
//
#include <hip/hip_runtime.h>

#define HDIM 128
#define NPOS 1024
#define NCOL 512
#define LN_EPS 1e-3f

// ---------------------------------------------------------------------------
// 3-kernel pipeline (kernel boundaries provide sync + coherence for free;
// rounds 1-4 proved in-kernel grid barriers are strictly worse here).
// Workspace layout (floats):
//   AcT  [128][1024]  centered seq-side A, k-major
//   BcT  [128][512]   centered col-side B, k-major
//   p[1024] v[1024] q[512] w[512]
//   rowsum[1024]  segsum[n_seq*512]  (atomics, zeroed by k1)
//   E    [1024][512]
//   segid[1024] (int)
// ---------------------------------------------------------------------------

__device__ __forceinline__ int seg_of(int i, const int* __restrict__ lens, int n_seq) {
    int cum = 0;
    for (int s = 0; s < n_seq; ++s) {
        cum += lens[s];
        if (i < cum) return s;
    }
    return n_seq - 1;
}

// ===========================================================================
// k1: 192 blocks x 512 threads. Block b handles 8 rows (seq side b<128,
// col side otherwise). Thread (r = t>>7, h = t&127) computes rows r and r+4:
// each W column load feeds BOTH rows' FMAs (2x W-traffic amortization vs the
// 4-row version; 192 blocks = exactly <=1 block/CU, no serialization round).
// Transposed store is 2x float4 = 32B/thread (was 16B).
// ===========================================================================
extern "C" __global__ void __launch_bounds__(512)
k1_precompute(const float* __restrict__ seq_feat, const float* __restrict__ col_feat,
              const float* __restrict__ Ws, const float* __restrict__ bsv,
              const float* __restrict__ Wc, const float* __restrict__ bcv,
              const float* __restrict__ Wm, const float* __restrict__ bmv,
              const float* __restrict__ gam, const float* __restrict__ Wo,
              const int* __restrict__ lens, int n_seq,
              float* __restrict__ AcT, float* __restrict__ BcT,
              float* __restrict__ p_arr, float* __restrict__ v_arr,
              float* __restrict__ q_arr, float* __restrict__ w_arr,
              float* __restrict__ sums, int* __restrict__ segid)
{
    __shared__ float xs[8][HDIM];
    __shared__ float ds_[8][HDIM];
    __shared__ float partm0[8], partm1[8], partp0[8], partp1[8], partv0[8], partv1[8];
    __shared__ float mus[8];

    const int t    = threadIdx.x;
    const int b    = blockIdx.x;
    const int h    = t & 127;
    const int r    = t >> 7;       // 0..3 (uniform per wave); thread owns rows r, r+4
    const int wv   = t >> 6;       // wave 0..7
    const int lane = t & 63;

    // housekeeping: zero accumulators + fill segid LUT
    {
        const int nsums = NPOS + n_seq * NCOL;
        int idx = b * 512 + t;
        if (idx < nsums) sums[idx] = 0.f;
        int idx2 = idx - nsums;
        if (idx2 >= 0 && idx2 < NPOS) segid[idx2] = seg_of(idx2, lens, n_seq);
    }

    const bool  is_seq = (b < NPOS / 8);
    const int   i0 = (is_seq ? b : (b - NPOS / 8)) * 8;
    const float* X  = is_seq ? seq_feat : col_feat;
    const float* W1 = is_seq ? Ws : Wc;
    const float* b1 = is_seq ? bsv : bcv;

    // stage 8 input rows into LDS (256 threads x float4)
    if (t < 256) {
        int rr = t >> 5, k4 = (t & 31) * 4;
        *(float4*)&xs[rr][k4] = *(const float4*)&X[(i0 + rr) * HDIM + k4];
    }
    __syncthreads();

    // ---- stage 1: d = relu(x . W1[:,h] + b1[h]) for rows r and r+4 ----
    float d0, d1;
    {
        float a00 = 0.f, a01 = 0.f, a02 = 0.f, a03 = 0.f;
        float a10 = 0.f, a11 = 0.f, a12 = 0.f, a13 = 0.f;
        #pragma unroll 8
        for (int k = 0; k < HDIM; k += 4) {
            float4 x0 = *(const float4*)&xs[r][k];
            float4 x1 = *(const float4*)&xs[r + 4][k];
            float w0 = W1[(k + 0) * HDIM + h];
            float w1 = W1[(k + 1) * HDIM + h];
            float w2 = W1[(k + 2) * HDIM + h];
            float w3 = W1[(k + 3) * HDIM + h];
            a00 += x0.x * w0; a01 += x0.y * w1; a02 += x0.z * w2; a03 += x0.w * w3;
            a10 += x1.x * w0; a11 += x1.y * w1; a12 += x1.z * w2; a13 += x1.w * w3;
        }
        const float bb = b1[h];
        d0 = fmaxf(bb + ((a00 + a01) + (a02 + a03)), 0.f);
        d1 = fmaxf(bb + ((a10 + a11) + (a12 + a13)), 0.f);
    }
    ds_[r][h] = d0;
    ds_[r + 4][h] = d1;
    __syncthreads();

    // ---- stage 2: aa = d . Wm[:,h] (+ bm on col side) for rows r and r+4 ----
    float aa0, aa1;
    {
        float a00 = 0.f, a01 = 0.f, a02 = 0.f, a03 = 0.f;
        float a10 = 0.f, a11 = 0.f, a12 = 0.f, a13 = 0.f;
        #pragma unroll 8
        for (int k = 0; k < HDIM; k += 4) {
            float4 x0 = *(const float4*)&ds_[r][k];
            float4 x1 = *(const float4*)&ds_[r + 4][k];
            float w0 = Wm[(k + 0) * HDIM + h];
            float w1 = Wm[(k + 1) * HDIM + h];
            float w2 = Wm[(k + 2) * HDIM + h];
            float w3 = Wm[(k + 3) * HDIM + h];
            a00 += x0.x * w0; a01 += x0.y * w1; a02 += x0.z * w2; a03 += x0.w * w3;
            a10 += x1.x * w0; a11 += x1.y * w1; a12 += x1.z * w2; a13 += x1.w * w3;
        }
        const float bb = is_seq ? 0.f : bmv[h];
        aa0 = bb + ((a00 + a01) + (a02 + a03));
        aa1 = bb + ((a10 + a11) + (a12 + a13));
    }

    // ---- row means (butterfly over the 2 waves holding the row pair) ----
    {
        float s0 = aa0, s1 = aa1;
        #pragma unroll
        for (int off = 32; off; off >>= 1) {
            s0 += __shfl_xor(s0, off, 64);
            s1 += __shfl_xor(s1, off, 64);
        }
        if (lane == 0) { partm0[wv] = s0; partm1[wv] = s1; }
    }
    __syncthreads();
    if (t < 4) {
        mus[t]     = (partm0[2 * t] + partm0[2 * t + 1]) * (1.f / HDIM);
        mus[t + 4] = (partm1[2 * t] + partm1[2 * t + 1]) * (1.f / HDIM);
    }
    __syncthreads();

    const float a0 = aa0 - mus[r];
    const float a1 = aa1 - mus[r + 4];
    const float gw = gam[h] * Wo[h];

    // ---- p = dot(a, gamma*Wo), v = mean(a^2) for both rows ----
    {
        float sp0 = a0 * gw, sv0 = a0 * a0;
        float sp1 = a1 * gw, sv1 = a1 * a1;
        #pragma unroll
        for (int off = 32; off; off >>= 1) {
            sp0 += __shfl_xor(sp0, off, 64);
            sv0 += __shfl_xor(sv0, off, 64);
            sp1 += __shfl_xor(sp1, off, 64);
            sv1 += __shfl_xor(sv1, off, 64);
        }
        if (lane == 0) { partp0[wv] = sp0; partv0[wv] = sv0; partp1[wv] = sp1; partv1[wv] = sv1; }
    }
    xs[r][h] = a0;        // reuse xs for transpose staging
    xs[r + 4][h] = a1;
    __syncthreads();
    if (t < 8) {
        float pv, vv;
        if (t < 4) {
            pv = partp0[2 * t] + partp0[2 * t + 1];
            vv = (partv0[2 * t] + partv0[2 * t + 1]) * (1.f / HDIM);
        } else {
            const int u = t - 4;
            pv = partp1[2 * u] + partp1[2 * u + 1];
            vv = (partv1[2 * u] + partv1[2 * u + 1]) * (1.f / HDIM);
        }
        (is_seq ? p_arr : q_arr)[i0 + t] = pv;
        (is_seq ? v_arr : w_arr)[i0 + t] = vv;
    }
    // transposed (k-major) store: row h gets the 8 centered values (32B/thread)
    if (t < 128) {
        float4 st0 = make_float4(xs[0][t], xs[1][t], xs[2][t], xs[3][t]);
        float4 st1 = make_float4(xs[4][t], xs[5][t], xs[6][t], xs[7][t]);
        if (is_seq) {
            *(float4*)&AcT[t * NPOS + i0]     = st0;
            *(float4*)&AcT[t * NPOS + i0 + 4] = st1;
        } else {
            *(float4*)&BcT[t * NCOL + i0]     = st0;
            *(float4*)&BcT[t * NCOL + i0 + 4] = st1;
        }
    }
}

// ===========================================================================
// k2: tiled fp32 GEMM dot(a_i,b_j), K=128, fused exp-epilogue + sum atomics.
// Tile 32 rows x 64 cols, 512 threads: waves 0-3 take k<64, waves 4-7 k>=64,
// combine partials through LDS. LDS <=64KB via union reuse.
// ===========================================================================
#define AS_STR 36
#define BS_STR 68

union K2Smem {
    struct { float As[128 * AS_STR]; float Bs[128 * BS_STR]; } s;
    struct { float comb[8 * 256]; float redr[512]; float redc[1024]; } r;
};

extern "C" __global__ void __launch_bounds__(512)
k2_gemm(const float* __restrict__ AcT, const float* __restrict__ BcT,
        const float* __restrict__ p_arr, const float* __restrict__ v_arr,
        const float* __restrict__ q_arr, const float* __restrict__ w_arr,
        const int* __restrict__ segid, int n_seq,
        float* __restrict__ E, float* __restrict__ rowsum, float* __restrict__ segsum)
{
    __shared__ K2Smem sm;

    const int t  = threadIdx.x;
    const int tt = t & 255;
    const int tc = tt & 15;      // col group (4 cols)
    const int tr = tt >> 4;      // row group (2 rows)
    const int kbase = (t >> 8) * 64;
    const int i0 = blockIdx.x * 32;
    const int j0 = blockIdx.y * 64;

    // stage A tile (128k x 32m) and B tile (128k x 64n), all 512 threads
    #pragma unroll
    for (int u = 0; u < 2; ++u) {
        int fid = t + 512 * u;                  // 0..1023
        int k = fid >> 3, m4 = fid & 7;
        *(float4*)&sm.s.As[k * AS_STR + 4 * m4] = *(const float4*)&AcT[k * NPOS + i0 + 4 * m4];
    }
    #pragma unroll
    for (int u = 0; u < 4; ++u) {
        int fid = t + 512 * u;                  // 0..2047
        int k = fid >> 4, n4 = fid & 15;
        *(float4*)&sm.s.Bs[k * BS_STR + 4 * n4] = *(const float4*)&BcT[k * NCOL + j0 + 4 * n4];
    }
    __syncthreads();

    float acc[8] = {0.f, 0.f, 0.f, 0.f, 0.f, 0.f, 0.f, 0.f};
    #pragma unroll 4
    for (int k = kbase; k < kbase + 64; ++k) {
        float2 a2 = *(const float2*)&sm.s.As[k * AS_STR + 2 * tr];
        float4 b4 = *(const float4*)&sm.s.Bs[k * BS_STR + 4 * tc];
        acc[0] += a2.x * b4.x; acc[1] += a2.x * b4.y; acc[2] += a2.x * b4.z; acc[3] += a2.x * b4.w;
        acc[4] += a2.y * b4.x; acc[5] += a2.y * b4.y; acc[6] += a2.y * b4.z; acc[7] += a2.y * b4.w;
    }

    const int seg_lo = segid[i0];
    const int seg_hi = segid[i0 + 31];
    __syncthreads();   // all waves done with As/Bs; union region reusable

    if (t >= 256) {
        #pragma unroll
        for (int j = 0; j < 8; ++j) sm.r.comb[j * 256 + tt] = acc[j];
    }
    __syncthreads();

    float e[2][4];
    if (t < 256) {
        #pragma unroll
        for (int j = 0; j < 8; ++j) acc[j] += sm.r.comb[j * 256 + tt];

        const int jj = j0 + 4 * tc;
        float4 q4 = *(const float4*)&q_arr[jj];
        float4 w4 = *(const float4*)&w_arr[jj];
        float rs[2];
        #pragma unroll
        for (int mm = 0; mm < 2; ++mm) {
            const int i = i0 + 2 * tr + mm;
            const float pi = p_arr[i];
            const float vi = v_arr[i];
            e[mm][0] = __expf((pi + q4.x) * rsqrtf(vi + w4.x + acc[4*mm+0] * (2.f/HDIM) + LN_EPS));
            e[mm][1] = __expf((pi + q4.y) * rsqrtf(vi + w4.y + acc[4*mm+1] * (2.f/HDIM) + LN_EPS));
            e[mm][2] = __expf((pi + q4.z) * rsqrtf(vi + w4.z + acc[4*mm+2] * (2.f/HDIM) + LN_EPS));
            e[mm][3] = __expf((pi + q4.w) * rsqrtf(vi + w4.w + acc[4*mm+3] * (2.f/HDIM) + LN_EPS));
            rs[mm] = e[mm][0] + e[mm][1] + e[mm][2] + e[mm][3];
            *(float4*)&E[i * NCOL + jj] = make_float4(e[mm][0], e[mm][1], e[mm][2], e[mm][3]);
        }
        sm.r.redr[(2 * tr + 0) * 16 + tc] = rs[0];
        sm.r.redr[(2 * tr + 1) * 16 + tc] = rs[1];
        #pragma unroll
        for (int u = 0; u < 4; ++u)
            sm.r.redc[(4 * tc + u) * 16 + tr] = e[0][u] + e[1][u];
    }
    __syncthreads();

    if (t < 32) {
        float s = 0.f;
        #pragma unroll
        for (int m = 0; m < 16; ++m) s += sm.r.redr[t * 16 + m];
        atomicAdd(&rowsum[i0 + t], s);
    } else if (t >= 32 && t < 96 && seg_lo == seg_hi) {
        int c = t - 32;
        float s = 0.f;
        #pragma unroll
        for (int m = 0; m < 16; ++m) s += sm.r.redc[c * 16 + m];
        atomicAdd(&segsum[seg_lo * NCOL + j0 + c], s);
    }
    if (seg_lo != seg_hi && t < 256) {
        // generic path: tile crosses a segment boundary (not hit for 8x128)
        #pragma unroll
        for (int mm = 0; mm < 2; ++mm) {
            const int i = i0 + 2 * tr + mm;
            const int sg = segid[i];
            #pragma unroll
            for (int u = 0; u < 4; ++u)
                atomicAdd(&segsum[sg * NCOL + j0 + 4 * tc + u], e[mm][u]);
        }
    }
}

// ===========================================================================
// k3: out = M_c + M_s - M_c*M_s
// ===========================================================================
extern "C" __global__ void __launch_bounds__(256)
k3_final(const float* __restrict__ E, const float* __restrict__ rowsum,
         const float* __restrict__ segsum, const int* __restrict__ segid,
         float* __restrict__ out)
{
    const int gid = blockIdx.x * 256 + threadIdx.x;   // 131072 float4 groups
    const int i = gid >> 7;
    const int j = (gid & 127) * 4;

    float4 e4 = *(const float4*)&E[i * NCOL + j];
    const float invr = 1.f / rowsum[i];
    const int sg = segid[i];
    float4 s4 = *(const float4*)&segsum[sg * NCOL + j];

    float4 o;
    { float mc = e4.x * invr, ms = e4.x / s4.x; o.x = mc + ms - mc * ms; }
    { float mc = e4.y * invr, ms = e4.y / s4.y; o.y = mc + ms - mc * ms; }
    { float mc = e4.z * invr, ms = e4.z / s4.z; o.z = mc + ms - mc * ms; }
    { float mc = e4.w * invr, ms = e4.w / s4.w; o.w = mc + ms - mc * ms; }
    *(float4*)&out[i * NCOL + j] = o;
}

// ===========================================================================
extern "C" void kernel_launch(void* const* d_in, const int* in_sizes, int n_in,
                              void* d_out, int out_size, void* d_ws, size_t ws_size,
                              hipStream_t stream) {
    const float* seq_feat = (const float*)d_in[0];
    const float* col_feat = (const float*)d_in[1];
    const int*   lens     = (const int*)d_in[2];
    const float* Ws   = (const float*)d_in[3];
    const float* bs   = (const float*)d_in[4];
    const float* Wc   = (const float*)d_in[5];
    const float* bc   = (const float*)d_in[6];
    const float* Wm   = (const float*)d_in[7];
    const float* bm   = (const float*)d_in[8];
    const float* gam  = (const float*)d_in[9];
    // d_in[10] = beta, d_in[12] = bo: cancel in both normalizations
    const float* Wo   = (const float*)d_in[11];
    float* out = (float*)d_out;
    const int n_seq = in_sizes[2];

    float* ws     = (float*)d_ws;
    float* AcT    = ws;                    // 128*1024
    float* BcT    = AcT + HDIM * NPOS;     // 128*512
    float* p      = BcT + HDIM * NCOL;     // 1024
    float* v      = p + NPOS;              // 1024
    float* q      = v + NPOS;              // 512
    float* w      = q + NCOL;              // 512
    float* sums   = w + NCOL;              // rowsum 1024 + segsum n_seq*512
    float* rowsum = sums;
    float* segsum = sums + NPOS;
    float* E      = segsum + n_seq * NCOL; // 1024*512
    int*   segid  = (int*)(E + NPOS * NCOL); // 1024 ints

    hipLaunchKernelGGL(k1_precompute, dim3(NPOS / 8 + NCOL / 8), dim3(512), 0, stream,
                       seq_feat, col_feat, Ws, bs, Wc, bc, Wm, bm, gam, Wo,
                       lens, n_seq, AcT, BcT, p, v, q, w, sums, segid);
    hipLaunchKernelGGL(k2_gemm, dim3(NPOS / 32, NCOL / 64), dim3(512), 0, stream,
                       AcT, BcT, p, v, q, w, segid, n_seq, E, rowsum, segsum);
    hipLaunchKernelGGL(k3_final, dim3((NPOS * NCOL / 4) / 256), dim3(256), 0, stream,
                       E, rowsum, segsum, segid, out);
}